// Round 6
// baseline (270.989 us; speedup 1.0000x reference)
//
#include <hip/hip_runtime.h>
#include <stdint.h>

// UKF (affine motion => exact Kalman filter). Inputs fp32, outputs fp32.
//
// R5: octet groups -> 128B-contiguous flush stores (1x write amp).
// R6: phase-staggered flushes, M=K*S=Pxz identity, v_rcp.
// R7: LDS temporal staging (killed reg-staging hazards + selects).
// R8: all-lane flush (best: ~95us/dispatch).
// R9: redundancy 16 (2x occupancy): BW FELL 1.94->1.63 TB/s => the
//     concurrency theory is dead. REVERTED to R8 structure.
// R10/R11 (this round): NON-TEMPORAL output stores, single isolated change.
//   Every kernel R5-R9 lands at dur == hbm_bytes / ~1.9 TB/s despite
//   wildly different staging/flush/occupancy => throughput wall for this
//   write pattern. Stores are 128B-contiguous but NOT 128B-aligned
//   (rows = 400B), zero-reuse, and dirty partial lines sit in L2 for
//   ~30us between epochs => suspect the L2 allocate/evict path caps the
//   drain. NT stores (MUBUF 'nt') skip L2 allocation for the one-shot
//   165MB stream. R10's compile error: the builtin needs a NATIVE clang
//   vector type, not HIP_vector_type -> ext_vector_type(4) alias.

typedef float floatx4 __attribute__((ext_vector_type(4)));

static constexpr float DTc  = 0.1f;
static constexpr float HDT2 = 0.5f * DTc * DTc;
static constexpr int SS = 68;                  // dwords per window slot (16 rows x 4 + pad)
static constexpr int GS = 8 * SS + 4;          // 548 dwords per group
static constexpr int LDS_BYTES = 32 * GS * 4;  // 70144 B per block

__global__ __launch_bounds__(256, 2) void ukf_r11(
    const float* __restrict__ meas,   // (B, 2, S)
    const float* __restrict__ stin,   // (B, 4)
    const float* __restrict__ covin,  // (B, 4, 4)
    const float* __restrict__ ctrl,   // (B, S, 2)
    const float* __restrict__ Qp,     // (4,4)
    const float* __restrict__ Rp,     // (2,2)
    float* __restrict__ out,          // preds (B,2,S) | states (B,4,S) | covs (B,4,4,S)
    int B, int S)
{
    extern __shared__ float lds[];

    const int tid  = blockIdx.x * 256 + threadIdx.x;
    const int b    = tid >> 3;             // 8 lanes per batch element
    const int myj  = threadIdx.x & 7;      // window index within tile / lane role
    if (b >= B) return;
    const int lane = threadIdx.x & 63;
    const int rrow = lane >> 3;            // 0..7 : row-cluster within wave
    const int wb   = b - rrow;             // wave's base batch element
    const int g    = threadIdx.x >> 3;     // block-level group 0..31
    const int wg8  = (threadIdx.x >> 6) << 3;  // wave's first block-group
    const int phase = b & 7;               // capture/flush phase stagger

    float* ldsg = lds + g * GS;            // this group's staging region

    float4 s4 = *reinterpret_cast<const float4*>(stin + (size_t)b * 4);
    float x0 = s4.x, x1 = s4.y, x2 = s4.z, x3 = s4.w;

    float p00, p01, p02, p03, p11, p12, p13, p22, p23, p33;
    {
        const float4* pc = reinterpret_cast<const float4*>(covin + (size_t)b * 16);
        float4 r0 = pc[0], r1 = pc[1], r2 = pc[2], r3 = pc[3];
        p00 = r0.x; p01 = r0.y; p02 = r0.z; p03 = r0.w;
        p11 = r1.y; p12 = r1.z; p13 = r1.w; p22 = r2.z; p23 = r2.w; p33 = r3.w;
    }
    float q00, q01, q02, q03, q11, q12, q13, q22, q23, q33;
    {
        const float4* pq = reinterpret_cast<const float4*>(Qp);
        float4 r0 = pq[0], r1 = pq[1], r2 = pq[2], r3 = pq[3];
        q00 = r0.x; q01 = r0.y; q02 = r0.z; q03 = r0.w;
        q11 = r1.y; q12 = r1.z; q13 = r1.w; q22 = r2.z; q23 = r2.w; q33 = r3.w;
    }
    float R00, R01, R10, R11;
    {
        float4 r = *reinterpret_cast<const float4*>(Rp);
        R00 = r.x; R01 = r.y; R10 = r.z; R11 = r.w;
    }

    const float4* pm0 = reinterpret_cast<const float4*>(meas + (size_t)b * 2 * S);
    const float4* pm1 = reinterpret_cast<const float4*>(meas + (size_t)b * 2 * S + S);
    const float4* pu  = reinterpret_cast<const float4*>(ctrl + (size_t)b * S * 2);

    const int NT = S / 4;                  // 4-step sub-tiles (25 for S=100)

    // ---- per-lane flush constants (3 passes; item = row x window) ----
    // out rows: 0,1 = preds; 2..5 = states; 6..21 = covs (4x4 via tri map)
    int      ldsoff[3];    // byte offset within flushing group's region
    uint32_t rbase[3];     // dword offset in out for batch wb, this row, +4*myj
    uint32_t mult[3];      // per-batch row-region stride (rr*S dwords)
    bool     act[3];
    {
        const int map16[16] = {0,1,2,3, 1,4,5,6, 2,5,7,8, 3,6,8,9};
#pragma unroll
        for (int p = 0; p < 3; ++p) {
            const int row = p * 8 + rrow;
            act[p] = (row < 22);
            const int tri = (row < 6) ? row : (row < 22 ? 6 + map16[row - 6] : 0);
            ldsoff[p] = (myj * SS + tri * 4) * 4;
            int rr, rowIn; uint32_t base0;
            if (row < 2)      { rr = 2;  rowIn = row;                   base0 = 0u; }
            else if (row < 6) { rr = 4;  rowIn = row - 2;               base0 = (uint32_t)B * 2u * (uint32_t)S; }
            else              { rr = 16; rowIn = (row < 22 ? row - 6 : 0); base0 = (uint32_t)B * 6u * (uint32_t)S; }
            mult[p]  = (uint32_t)(rr * S);
            rbase[p] = base0 + (uint32_t)wb * mult[p] + (uint32_t)(rowIn * S) + (uint32_t)(4 * myj);
        }
    }

    float4 m0 = pm0[0], m1 = pm1[0], u0 = pu[0], u1 = pu[1];

    for (int sub = 0; sub < NT + 7; ++sub) {
        float4 nm0 = make_float4(0, 0, 0, 0), nm1 = nm0, nu0 = nm0, nu1 = nm0;
        if (sub + 1 < NT) {
            nm0 = pm0[sub + 1];
            nm1 = pm1[sub + 1];
            nu0 = pu[2 * sub + 2];
            nu1 = pu[2 * sub + 3];
        }

        if (sub < NT) {
            const float zb0[4] = { m0.x, m0.y, m0.z, m0.w };
            const float zb1[4] = { m1.x, m1.y, m1.z, m1.w };
            const float uxb[4] = { u0.x, u0.z, u1.x, u1.z };
            const float uyb[4] = { u0.y, u0.w, u1.y, u1.w };

            float* cap = ldsg + ((sub + phase) & 7) * SS;

#pragma unroll
            for (int k = 0; k < 4; ++k) {
                const float ux = uxb[k], uy = uyb[k];

                const float xp0 = x0 + DTc * x2 + HDT2 * ux;
                const float xp1 = x1 + DTc * x3 + HDT2 * uy;
                const float xp2 = x2 + DTc * ux;
                const float xp3 = x3 + DTc * uy;

                const float FP00 = p00 + DTc * p02, FP01 = p01 + DTc * p12;
                const float FP02 = p02 + DTc * p22, FP03 = p03 + DTc * p23;
                const float FP11 = p11 + DTc * p13, FP12 = p12 + DTc * p23;
                const float FP13 = p13 + DTc * p33;

                const float a00 = FP00 + DTc * FP02, a01 = FP01 + DTc * FP03;
                const float a02 = FP02, a03 = FP03;
                const float a11 = FP11 + DTc * FP13, a12 = FP12, a13 = FP13;
                const float a22 = p22, a23 = p23, a33 = p33;

                const float s00 = a00 + R00, s01 = a01 + R01;
                const float s10 = a01 + R10, s11 = a11 + R11;
                const float rdet = __builtin_amdgcn_rcpf(s00 * s11 - s01 * s10);
                const float i00 =  s11 * rdet, i01 = -s01 * rdet;
                const float i10 = -s10 * rdet, i11 =  s00 * rdet;

                const float K00 = a00*i00 + a01*i10, K01 = a00*i01 + a01*i11;
                const float K10 = a01*i00 + a11*i10, K11 = a01*i01 + a11*i11;
                const float K20 = a02*i00 + a12*i10, K21 = a02*i01 + a12*i11;
                const float K30 = a03*i00 + a13*i10, K31 = a03*i01 + a13*i11;

                const float in0 = zb0[k] - xp0, in1 = zb1[k] - xp1;
                const float xn0 = xp0 + K00*in0 + K01*in1;
                const float xn1 = xp1 + K10*in0 + K11*in1;
                const float xn2 = xp2 + K20*in0 + K21*in1;
                const float xn3 = xp3 + K30*in0 + K31*in1;

                // M = K*S = Pxz = a[:,0:2] -> P = a + Q - Pxz*K^T
                p00 = (a00 + q00) - a00*K00 - a01*K01;
                p01 = (a01 + q01) - a00*K10 - a01*K11;
                p02 = (a02 + q02) - a00*K20 - a01*K21;
                p03 = (a03 + q03) - a00*K30 - a01*K31;
                p11 = (a11 + q11) - a01*K10 - a11*K11;
                p12 = (a12 + q12) - a01*K20 - a11*K21;
                p13 = (a13 + q13) - a01*K30 - a11*K31;
                p22 = (a22 + q22) - a02*K20 - a12*K21;
                p23 = (a23 + q23) - a02*K30 - a12*K31;
                p33 = (a33 + q33) - a03*K30 - a13*K31;

                x0 = xn0; x1 = xn1; x2 = xn2; x3 = xn3;

                // capture: lane 0 of each group writes this step into the slot;
                // [row][k] layout, pairs fuse to ds_write2_b32.
                if (myj == 0) {
                    cap[ 0*4 + k] = xp0;  cap[ 1*4 + k] = xp1;
                    cap[ 2*4 + k] = xn0;  cap[ 3*4 + k] = xn1;
                    cap[ 4*4 + k] = xn2;  cap[ 5*4 + k] = xn3;
                    cap[ 6*4 + k] = p00;  cap[ 7*4 + k] = p01;
                    cap[ 8*4 + k] = p02;  cap[ 9*4 + k] = p03;
                    cap[10*4 + k] = p11;  cap[11*4 + k] = p12;
                    cap[12*4 + k] = p13;  cap[13*4 + k] = p22;
                    cap[14*4 + k] = p23;  cap[15*4 + k] = p33;
                }
            }
        }

        // ---- all-lane flush of group gf: (sub + phase(gf)) & 7 == 7 ----
        // wave-uniform gf; lane l handles (row = p*8 + (l>>3), window j = l&7);
        // slot == j at flush time. 8-lane clusters write 128B contiguous.
        // NON-TEMPORAL: zero-reuse one-shot stream, skip L2 allocation.
        {
            const int gf = (7 - sub - wb) & 7;
            const float* fsrc = lds + (size_t)(wg8 + gf) * GS;
            const int w = sub - 7 + myj;
            const bool wok = (w >= 0) && (w < NT);
            const int dsub4 = (sub - 7) * 4;
#pragma unroll
            for (int p = 0; p < 3; ++p) {
                const floatx4 v = *reinterpret_cast<const floatx4*>(
                    reinterpret_cast<const char*>(fsrc) + ldsoff[p]);
                if (wok && act[p]) {
                    const int off = (int)rbase[p] + gf * (int)mult[p] + dsub4;
                    __builtin_nontemporal_store(v, reinterpret_cast<floatx4*>(out + off));
                }
            }
        }

        m0 = nm0; m1 = nm1; u0 = nu0; u1 = nu1;
    }
}

extern "C" void kernel_launch(void* const* d_in, const int* in_sizes, int n_in,
                              void* d_out, int out_size, void* d_ws, size_t ws_size,
                              hipStream_t stream) {
    // Identify inputs by element count (order-robust):
    int iR = -1, iQ = -1, iMeas = -1, iCtrl = -1, iState = -1, iCov = -1;
    for (int i = 0; i < n_in; i++) {
        if (in_sizes[i] == 4 && iR < 0) iR = i;
        else if (in_sizes[i] == 16 && iQ < 0) iQ = i;
    }
    for (int i = 0; i < n_in && iMeas < 0; i++) {
        if (i == iR || i == iQ) continue;
        for (int j = i + 1; j < n_in; j++) {
            if (j == iR || j == iQ) continue;
            if (in_sizes[i] == in_sizes[j]) { iMeas = i; iCtrl = j; break; }
        }
    }
    int rem[2], nrem = 0;
    for (int i = 0; i < n_in && nrem < 2; i++) {
        if (i == iR || i == iQ || i == iMeas || i == iCtrl) continue;
        rem[nrem++] = i;
    }
    if (in_sizes[rem[0]] > in_sizes[rem[1]]) { iCov = rem[0]; iState = rem[1]; }
    else                                     { iCov = rem[1]; iState = rem[0]; }

    const float* meas  = (const float*)d_in[iMeas];
    const float* stin  = (const float*)d_in[iState];
    const float* covin = (const float*)d_in[iCov];
    const float* ctrl  = (const float*)d_in[iCtrl];
    const float* Qp    = (const float*)d_in[iQ];
    const float* Rp    = (const float*)d_in[iR];
    float* out = (float*)d_out;

    const int B = in_sizes[iState] / 4;
    const int S = in_sizes[iMeas] / (2 * B);

    // 8 threads per batch element, 256-thread blocks, 70144 B dynamic LDS
    const int total = B * 8;
    ukf_r11<<<dim3((total + 255) / 256), dim3(256), LDS_BYTES, stream>>>(
        meas, stin, covin, ctrl, Qp, Rp, out, B, S);
}

// Round 7
// 205.694 us; speedup vs baseline: 1.3174x; 1.3174x over previous
//
#include <hip/hip_runtime.h>
#include <stdint.h>

// UKF (affine motion => exact Kalman filter). Inputs fp32, outputs fp32.
//
// R5: octet groups -> 128B-contiguous flush stores (1x write amp).
// R6: phase-staggered flushes, M=K*S=Pxz identity, v_rcp.
// R7: LDS temporal staging. R8: all-lane flush (best ~95us/dispatch).
// R9: 2x occupancy -> BW FELL (concurrency theory dead).
// R11: NT stores -> 1.28 TB/s (WORSE) => L2 was merging partial lines.
// R12 (this round): PER-ROW PHASE-ALIGNED FLUSHES for covs.
//   Mechanism (fits all R5-R11 data): every flush chunk is 128B contiguous
//   but 16B-grain MISALIGNED (rows are 400B), so EVERY line is assembled
//   by two flush events ~30us apart; L2 evicts between (6.5MB/XCD/epoch >
//   4MB) => every line written to HBM TWICE as sector-masked partials
//   (WRITE_SIZE counts dirty sectors => looks like 1.15x; DRAM cost ~2x).
//   Fix: row with global row-index === rho (mod 8) is misaligned by
//   16*rho; flushing it at subs === 7-rho (mod 8) makes chunk start
//   16*rho + 16*(sub-7) === 0 (mod 128): every chunk = ONE full line,
//   single event, fully dirty. covs rows (72% of bytes): global index
//   16b+i => rho = i&7 (b-independent!): per sub, flush covs entries
//   {tau, tau+8}, tau=(7-sub)&7, for ALL 8 groups of the wave (2 wave-
//   stores, each 8-lane cluster = one aligned line). preds/states keep
//   the R8 group-staggered path (passO, rows 0-5).

typedef float floatx4 __attribute__((ext_vector_type(4)));

static constexpr float DTc  = 0.1f;
static constexpr float HDT2 = 0.5f * DTc * DTc;
static constexpr int SS = 68;                  // dwords per window slot (16 rows x 4 + pad)
static constexpr int GS = 8 * SS + 4;          // 548 dwords per group
static constexpr int LDS_BYTES = 32 * GS * 4;  // 70144 B per block

__global__ __launch_bounds__(256, 2) void ukf_r12(
    const float* __restrict__ meas,   // (B, 2, S)
    const float* __restrict__ stin,   // (B, 4)
    const float* __restrict__ covin,  // (B, 4, 4)
    const float* __restrict__ ctrl,   // (B, S, 2)
    const float* __restrict__ Qp,     // (4,4)
    const float* __restrict__ Rp,     // (2,2)
    float* __restrict__ out,          // preds (B,2,S) | states (B,4,S) | covs (B,4,4,S)
    int B, int S)
{
    extern __shared__ float lds[];

    const int tid  = blockIdx.x * 256 + threadIdx.x;
    const int b    = tid >> 3;             // 8 lanes per batch element
    const int myj  = threadIdx.x & 7;      // window-lane within cluster
    if (b >= B) return;
    const int lane = threadIdx.x & 63;
    const int rrow = lane >> 3;            // 0..7 : item-cluster within wave
    const int wb   = b - rrow;             // wave's base batch element
    const int g    = threadIdx.x >> 3;     // block-level group 0..31
    const int wg8  = (threadIdx.x >> 6) << 3;  // wave's first block-group
    const int phase = b & 7;               // capture/flush phase stagger

    float* ldsg = lds + g * GS;            // this group's staging region

    float4 s4 = *reinterpret_cast<const float4*>(stin + (size_t)b * 4);
    float x0 = s4.x, x1 = s4.y, x2 = s4.z, x3 = s4.w;

    float p00, p01, p02, p03, p11, p12, p13, p22, p23, p33;
    {
        const float4* pc = reinterpret_cast<const float4*>(covin + (size_t)b * 16);
        float4 r0 = pc[0], r1 = pc[1], r2 = pc[2], r3 = pc[3];
        p00 = r0.x; p01 = r0.y; p02 = r0.z; p03 = r0.w;
        p11 = r1.y; p12 = r1.z; p13 = r1.w; p22 = r2.z; p23 = r2.w; p33 = r3.w;
    }
    float q00, q01, q02, q03, q11, q12, q13, q22, q23, q33;
    {
        const float4* pq = reinterpret_cast<const float4*>(Qp);
        float4 r0 = pq[0], r1 = pq[1], r2 = pq[2], r3 = pq[3];
        q00 = r0.x; q01 = r0.y; q02 = r0.z; q03 = r0.w;
        q11 = r1.y; q12 = r1.z; q13 = r1.w; q22 = r2.z; q23 = r2.w; q33 = r3.w;
    }
    float R00, R01, R10, R11;
    {
        float4 r = *reinterpret_cast<const float4*>(Rp);
        R00 = r.x; R01 = r.y; R10 = r.z; R11 = r.w;
    }

    const float4* pm0 = reinterpret_cast<const float4*>(meas + (size_t)b * 2 * S);
    const float4* pm1 = reinterpret_cast<const float4*>(meas + (size_t)b * 2 * S + S);
    const float4* pu  = reinterpret_cast<const float4*>(ctrl + (size_t)b * S * 2);

    const int NT = S / 4;                  // 4-step sub-tiles (25 for S=100)

    // ---- covs passes (A: entry tau, B: entry tau+8), aligned full lines ----
    // per-lane constants (dword offsets into out); per-sub uniform add.
    const int covs_base = B * 6 * S;                       // dwords
    const int b_local   = rrow;                            // covs: item = b
    const int cA = covs_base + (16 * (wb + b_local)) * S + 4 * (myj - 7);
    const int jb = myj + b_local;                          // for slot calc
    float* const ldsNbase = lds + (size_t)(wg8 + b_local) * GS;

    // ---- passO: preds/states rows 0..5 of staggered group gf (R8 path) ----
    int ldsoffO; int rbaseO, multO; const bool actO = (rrow < 6);
    {
        const int row = rrow;
        const int lrow = (row < 6) ? row : 0;              // LDS rows 0..5
        ldsoffO = myj * SS + lrow * 4;                     // dwords
        int rr, rowIn, base0;
        if (row < 2) { rr = 2; rowIn = row;               base0 = 0; }
        else         { rr = 4; rowIn = (row < 6) ? row - 2 : 0; base0 = B * 2 * S; }
        multO  = rr * S;
        rbaseO = base0 + wb * multO + rowIn * S + 4 * myj;
    }

    float4 m0 = pm0[0], m1 = pm1[0], u0 = pu[0], u1 = pu[1];

    for (int sub = 0; sub < NT + 7; ++sub) {
        float4 nm0 = make_float4(0, 0, 0, 0), nm1 = nm0, nu0 = nm0, nu1 = nm0;
        if (sub + 1 < NT) {
            nm0 = pm0[sub + 1];
            nm1 = pm1[sub + 1];
            nu0 = pu[2 * sub + 2];
            nu1 = pu[2 * sub + 3];
        }

        if (sub < NT) {
            const float zb0[4] = { m0.x, m0.y, m0.z, m0.w };
            const float zb1[4] = { m1.x, m1.y, m1.z, m1.w };
            const float uxb[4] = { u0.x, u0.z, u1.x, u1.z };
            const float uyb[4] = { u0.y, u0.w, u1.y, u1.w };

            float* cap = ldsg + ((sub + phase) & 7) * SS;

#pragma unroll
            for (int k = 0; k < 4; ++k) {
                const float ux = uxb[k], uy = uyb[k];

                const float xp0 = x0 + DTc * x2 + HDT2 * ux;
                const float xp1 = x1 + DTc * x3 + HDT2 * uy;
                const float xp2 = x2 + DTc * ux;
                const float xp3 = x3 + DTc * uy;

                const float FP00 = p00 + DTc * p02, FP01 = p01 + DTc * p12;
                const float FP02 = p02 + DTc * p22, FP03 = p03 + DTc * p23;
                const float FP11 = p11 + DTc * p13, FP12 = p12 + DTc * p23;
                const float FP13 = p13 + DTc * p33;

                const float a00 = FP00 + DTc * FP02, a01 = FP01 + DTc * FP03;
                const float a02 = FP02, a03 = FP03;
                const float a11 = FP11 + DTc * FP13, a12 = FP12, a13 = FP13;
                const float a22 = p22, a23 = p23, a33 = p33;

                const float s00 = a00 + R00, s01 = a01 + R01;
                const float s10 = a01 + R10, s11 = a11 + R11;
                const float rdet = __builtin_amdgcn_rcpf(s00 * s11 - s01 * s10);
                const float i00 =  s11 * rdet, i01 = -s01 * rdet;
                const float i10 = -s10 * rdet, i11 =  s00 * rdet;

                const float K00 = a00*i00 + a01*i10, K01 = a00*i01 + a01*i11;
                const float K10 = a01*i00 + a11*i10, K11 = a01*i01 + a11*i11;
                const float K20 = a02*i00 + a12*i10, K21 = a02*i01 + a12*i11;
                const float K30 = a03*i00 + a13*i10, K31 = a03*i01 + a13*i11;

                const float in0 = zb0[k] - xp0, in1 = zb1[k] - xp1;
                const float xn0 = xp0 + K00*in0 + K01*in1;
                const float xn1 = xp1 + K10*in0 + K11*in1;
                const float xn2 = xp2 + K20*in0 + K21*in1;
                const float xn3 = xp3 + K30*in0 + K31*in1;

                // M = K*S = Pxz = a[:,0:2] -> P = a + Q - Pxz*K^T
                p00 = (a00 + q00) - a00*K00 - a01*K01;
                p01 = (a01 + q01) - a00*K10 - a01*K11;
                p02 = (a02 + q02) - a00*K20 - a01*K21;
                p03 = (a03 + q03) - a00*K30 - a01*K31;
                p11 = (a11 + q11) - a01*K10 - a11*K11;
                p12 = (a12 + q12) - a01*K20 - a11*K21;
                p13 = (a13 + q13) - a01*K30 - a11*K31;
                p22 = (a22 + q22) - a02*K20 - a12*K21;
                p23 = (a23 + q23) - a02*K30 - a12*K31;
                p33 = (a33 + q33) - a03*K30 - a13*K31;

                x0 = xn0; x1 = xn1; x2 = xn2; x3 = xn3;

                // capture: lane 0 of each group writes this step into the slot
                if (myj == 0) {
                    cap[ 0*4 + k] = xp0;  cap[ 1*4 + k] = xp1;
                    cap[ 2*4 + k] = xn0;  cap[ 3*4 + k] = xn1;
                    cap[ 4*4 + k] = xn2;  cap[ 5*4 + k] = xn3;
                    cap[ 6*4 + k] = p00;  cap[ 7*4 + k] = p01;
                    cap[ 8*4 + k] = p02;  cap[ 9*4 + k] = p03;
                    cap[10*4 + k] = p11;  cap[11*4 + k] = p12;
                    cap[12*4 + k] = p13;  cap[13*4 + k] = p22;
                    cap[14*4 + k] = p23;  cap[15*4 + k] = p33;
                }
            }
        }

        // ================== flush (every sub) ==================
        {
            const int w   = sub - 7 + myj;                 // window = step-tile
            const bool wok = (w >= 0) && (w < NT);
            const int tau = (7 - sub) & 7;                 // covs row parity flushing now
            // LDS rows for covs entries tau / tau+8 (6 + map16[i], x4 dwords)
            const int ltA = 24 + 4 * (int)((0x65413210u >> (tau * 4)) & 0xFu);
            const int ltB = 24 + 4 * (int)((0x98638752u >> (tau * 4)) & 0xFu);
            // slot of window w for group (wb + b_local): (w + phase_b) & 7
            const int c8   = (sub + 1 + wb) & 7;
            const int slot = (c8 + jb) & 7;
            const int soff = slot * SS;
            const int dN   = 100 * tau + 4 * sub;          // per-sub covs add (dwords)

            // pass A: covs entry tau  -> full aligned 128B line per 8-lane cluster
            {
                const floatx4 v = *reinterpret_cast<const floatx4*>(ldsNbase + soff + ltA);
                if (wok)
                    *reinterpret_cast<floatx4*>(out + cA + dN) = v;
            }
            // pass B: covs entry tau+8
            {
                const floatx4 v = *reinterpret_cast<const floatx4*>(ldsNbase + soff + ltB);
                if (wok)
                    *reinterpret_cast<floatx4*>(out + cA + dN + 800) = v;
            }
            // pass O: preds/states rows 0..5 of staggered group gf (R8 path)
            {
                const int gf = (7 - sub - wb) & 7;
                const float* fsrcO = lds + (size_t)(wg8 + gf) * GS;
                const floatx4 v = *reinterpret_cast<const floatx4*>(fsrcO + ldsoffO);
                if (wok && actO)
                    *reinterpret_cast<floatx4*>(out + rbaseO + gf * multO + (sub - 7) * 4) = v;
            }
        }

        m0 = nm0; m1 = nm1; u0 = nu0; u1 = nu1;
    }
}

extern "C" void kernel_launch(void* const* d_in, const int* in_sizes, int n_in,
                              void* d_out, int out_size, void* d_ws, size_t ws_size,
                              hipStream_t stream) {
    // Identify inputs by element count (order-robust):
    int iR = -1, iQ = -1, iMeas = -1, iCtrl = -1, iState = -1, iCov = -1;
    for (int i = 0; i < n_in; i++) {
        if (in_sizes[i] == 4 && iR < 0) iR = i;
        else if (in_sizes[i] == 16 && iQ < 0) iQ = i;
    }
    for (int i = 0; i < n_in && iMeas < 0; i++) {
        if (i == iR || i == iQ) continue;
        for (int j = i + 1; j < n_in; j++) {
            if (j == iR || j == iQ) continue;
            if (in_sizes[i] == in_sizes[j]) { iMeas = i; iCtrl = j; break; }
        }
    }
    int rem[2], nrem = 0;
    for (int i = 0; i < n_in && nrem < 2; i++) {
        if (i == iR || i == iQ || i == iMeas || i == iCtrl) continue;
        rem[nrem++] = i;
    }
    if (in_sizes[rem[0]] > in_sizes[rem[1]]) { iCov = rem[0]; iState = rem[1]; }
    else                                     { iCov = rem[1]; iState = rem[0]; }

    const float* meas  = (const float*)d_in[iMeas];
    const float* stin  = (const float*)d_in[iState];
    const float* covin = (const float*)d_in[iCov];
    const float* ctrl  = (const float*)d_in[iCtrl];
    const float* Qp    = (const float*)d_in[iQ];
    const float* Rp    = (const float*)d_in[iR];
    float* out = (float*)d_out;

    const int B = in_sizes[iState] / 4;
    const int S = in_sizes[iMeas] / (2 * B);

    // 8 threads per batch element, 256-thread blocks, 70144 B dynamic LDS
    const int total = B * 8;
    ukf_r12<<<dim3((total + 255) / 256), dim3(256), LDS_BYTES, stream>>>(
        meas, stin, covin, ctrl, Qp, Rp, out, B, S);
}